// Round 15
// baseline (566.657 us; speedup 1.0000x reference)
//
#include <hip/hip_runtime.h>
#include <hip/hip_fp16.h>

#define N_NODES 100000
#define N_EDGES 1600000
#define DIN 24
#define DH 64
#define DOUT 12
#define NEG_SLOPE 0.01f
#define NS 49                      // node slices of 2048 (slice = d >> 11)
#define SLICE_N 2048
#define NC 4                       // edge chunks
#define EPC (N_EDGES / NC)         // 400000 edges per chunk
#define NTOT4 (N_NODES * NC)       // 400000 byte counters, layout [n*NC+c]
#define SCAN_BLK 4096
#define LDSW 72

// role block counts (1024-thread fused dispatches)
#define NB_HIST2 (NS * NC)                 // 196
#define NB_EMBED ((N_NODES * DH) / 1024)   // 6250
#define NB_SCANB ((NTOT4 + SCAN_BLK - 1) / SCAN_BLK)  // 98
#define NB_SCAN3 ((NTOT4 + 255) / 256)     // 1563
#define NB_SCAT (NS * NC)                  // 196
#define NB_NODE ((N_NODES + 255) / 256)    // 391 (16 waves x 16 nodes per block)
#define NB_AGG ((N_NODES + 7) / 8)         // 12500

typedef _Float16 half8_t __attribute__((ext_vector_type(8)));
typedef float floatx4 __attribute__((ext_vector_type(4)));

// ---------------- role bodies ----------------
__device__ __forceinline__ void dev_consts(const float* emb_e_W, const float* emb_e_b,
                                           const float* attn1, const float* attn2,
                                           float* consts) {
    int lane = threadIdx.x;
    if (lane >= 64) return;
    float w = emb_e_W[lane], b = emb_e_b[lane];
    float a1 = attn1[2 * DH + lane], a2 = attn2[2 * DH + lane];
    float c11 = w * a1, c01 = b * a1, c12 = w * a2, c02 = b * a2;
    for (int off = 32; off; off >>= 1) {
        c11 += __shfl_down(c11, off);
        c01 += __shfl_down(c01, off);
        c12 += __shfl_down(c12, off);
        c02 += __shfl_down(c02, off);
    }
    if (lane == 0) {
        consts[0] = c11; consts[1] = c01; consts[2] = c12; consts[3] = c02;
    }
}

// slice-private LDS histogram: block (s,c) counts chunk c's in-slice dst's in LDS
// byte counters; flush is a plain coalesced write. ZERO global atomics —
// round-13/14 lesson: device atomics cost ~32B write-through per op + ~23G/s
// rate floor; 1.6M of them was the 100-us pole of D1.
__device__ __forceinline__ void dev_hist2(int bid, const int* dst,
                                          unsigned char* deg) {
    __shared__ unsigned cnt[SLICE_N / 4];   // byte-packed, 2 KB
    int s = bid % NS, c = bid / NS;
    for (int i = threadIdx.x; i < SLICE_N / 4; i += 1024) cnt[i] = 0;
    __syncthreads();
    int nbase = s << 11;
    int start = c * EPC, end = start + EPC;
    for (int i = start + threadIdx.x; i < end; i += 1024) {
        int local = dst[i] - nbase;
        if ((unsigned)local < SLICE_N)
            atomicAdd(&cnt[local >> 2], 1u << ((local & 3) * 8));  // LDS atomic
    }
    __syncthreads();
    const unsigned char* cb = (const unsigned char*)cnt;
    for (int l = threadIdx.x; l < SLICE_N; l += 1024) {
        int n = nbase + l;
        if (n < N_NODES) deg[n * NC + c] = cb[l];   // per-(n,c) single writer
    }
}

__device__ __forceinline__ void dev_embed(int bid, const float* feats, const float* W,
                                          const float* b, float* h) {
    int idx = bid * 1024 + threadIdx.x;
    if (idx >= N_NODES * DH) return;
    int n = idx >> 6, o = idx & 63;
    const float* f = feats + n * DIN;
    const float* w = W + o * DIN;
    float acc = b[o];
#pragma unroll
    for (int k = 0; k < DIN; ++k) acc += f[k] * w[k];
    h[idx] = acc;
}

// atomic-free direct scatter: LDS cursors seeded from row_off4; csr2 written at
// final node-contiguous positions (no staging csr, no compact, no rank array)
__device__ __forceinline__ void dev_scatter2(int bid, const int* src, const int* dst,
                                             const float* e_w, const int* row_off4,
                                             unsigned* csr2) {
    __shared__ int cur[SLICE_N];            // 8 KB
    int s = bid % NS, c = bid / NS;
    int nbase = s << 11;
    for (int l = threadIdx.x; l < SLICE_N; l += 1024) {
        int n = nbase + l;
        cur[l] = (n < N_NODES) ? row_off4[n * NC + c] : 0;
    }
    __syncthreads();
    int start = c * EPC, end = start + EPC;
    for (int i = start + threadIdx.x; i < end; i += 1024) {
        int local = dst[i] - nbase;
        if ((unsigned)local < SLICE_N) {
            unsigned qv = (unsigned)(e_w[i] * 32768.f);
            if (qv > 32767u) qv = 32767u;
            unsigned w = (unsigned)src[i] | (qv << 17);
            int pos = atomicAdd(&cur[local], 1);   // LDS atomic, single block per (s,c)
            csr2[pos] = w;
        }
    }
}

// MFMA node GEMM: 16 nodes/wave, 16 waves/block (1024 thr), weights fp16 in LDS
__device__ __forceinline__ void dev_node(int bid, const float* h,
                                         const float* Wself, const float* Wfunc,
                                         const float* attn,
                                         __half* zh, float* hs,
                                         float* s_src, float* s_dst) {
    __shared__ _Float16 lds[2 * 64 * LDSW];
    int tid = threadIdx.x;
    for (int idx = tid; idx < 2 * 64 * 64; idx += 1024) {
        int mat = idx >> 12, rem = idx & 4095;
        int o = rem >> 6, k = rem & 63;
        float v = mat ? Wfunc[rem] : Wself[rem];
        lds[(mat * 64 + o) * LDSW + k] = (_Float16)v;
    }
    __syncthreads();

    int wave = tid >> 6, lane = tid & 63;
    int n0 = (bid * 16 + wave) * 16;
    if (n0 >= N_NODES) return;
    int quad = lane >> 4, lm = lane & 15;

    half8_t afrag[2];
    {
        const float4* hrow = (const float4*)(h + (size_t)(n0 + lm) * DH);
#pragma unroll
        for (int ks = 0; ks < 2; ++ks) {
            float4 p0 = hrow[ks * 8 + quad * 2];
            float4 p1 = hrow[ks * 8 + quad * 2 + 1];
            half8_t a;
            a[0] = (_Float16)p0.x; a[1] = (_Float16)p0.y;
            a[2] = (_Float16)p0.z; a[3] = (_Float16)p0.w;
            a[4] = (_Float16)p1.x; a[5] = (_Float16)p1.y;
            a[6] = (_Float16)p1.z; a[7] = (_Float16)p1.w;
            afrag[ks] = a;
        }
    }

    floatx4 accS[4], accF[4];
#pragma unroll
    for (int t = 0; t < 4; ++t) { accS[t] = (floatx4)0.f; accF[t] = (floatx4)0.f; }

    const _Float16* bS = lds;
    const _Float16* bF = lds + 64 * LDSW;
#pragma unroll
    for (int t = 0; t < 4; ++t) {
        int o = t * 16 + lm;
#pragma unroll
        for (int ks = 0; ks < 2; ++ks) {
            int hoff = o * LDSW + ks * 32 + quad * 8;
            half8_t b1 = *(const half8_t*)(bS + hoff);
            half8_t b2 = *(const half8_t*)(bF + hoff);
            accS[t] = __builtin_amdgcn_mfma_f32_16x16x32_f16(afrag[ks], b1, accS[t], 0, 0, 0);
            accF[t] = __builtin_amdgcn_mfma_f32_16x16x32_f16(afrag[ks], b2, accF[t], 0, 0, 0);
        }
    }

    float asv[4], adv[4];
#pragma unroll
    for (int t = 0; t < 4; ++t) {
        asv[t] = attn[t * 16 + lm];
        adv[t] = attn[DH + t * 16 + lm];
    }
    float ps[4] = {0.f, 0.f, 0.f, 0.f}, pd[4] = {0.f, 0.f, 0.f, 0.f};
#pragma unroll
    for (int t = 0; t < 4; ++t) {
#pragma unroll
        for (int r = 0; r < 4; ++r) {
            int node = n0 + quad * 4 + r;
            float zv = accF[t][r];
            zh[(size_t)node * DH + t * 16 + lm] = __float2half(zv);
            hs[(size_t)node * DH + t * 16 + lm] = accS[t][r];
            ps[r] += zv * asv[t];
            pd[r] += zv * adv[t];
        }
    }
#pragma unroll
    for (int r = 0; r < 4; ++r) {
        float p1 = ps[r], p2 = pd[r];
        for (int off = 8; off; off >>= 1) {
            p1 += __shfl_xor(p1, off);
            p2 += __shfl_xor(p2, off);
        }
        if (lm == 0) {
            s_src[n0 + quad * 4 + r] = p1;
            s_dst[n0 + quad * 4 + r] = p2;
        }
    }
}

// ---------------- fused dispatches ----------------
// D1: consts | hist2(LDS) | embed
__global__ void __launch_bounds__(1024, 4)
k_fuse1(const float* __restrict__ feats, const float* __restrict__ emb_h_W,
        const float* __restrict__ emb_h_b, float* __restrict__ h,
        const int* __restrict__ dst, unsigned char* __restrict__ deg,
        const float* __restrict__ emb_e_W, const float* __restrict__ emb_e_b,
        const float* __restrict__ attn1, const float* __restrict__ attn2,
        float* __restrict__ consts) {
    int bid = blockIdx.x;
    if (bid == 0) { dev_consts(emb_e_W, emb_e_b, attn1, attn2, consts); return; }
    bid -= 1;
    if (bid < NB_HIST2) { dev_hist2(bid, dst, deg); return; }
    dev_embed(bid - NB_HIST2, feats, emb_h_W, emb_h_b, h);
}

// D2: exclusive scan over the 400K byte counters -> row_off4 ints
__global__ void k_scanB(const unsigned* __restrict__ inW, int* __restrict__ out,
                        int* __restrict__ part) {
    __shared__ int lds[256];
    int t = threadIdx.x;
    int base = blockIdx.x * SCAN_BLK + t * 16;
    unsigned wv[4];
#pragma unroll
    for (int i = 0; i < 4; ++i) wv[i] = inW[(base >> 2) + i];  // padded alloc
    int v[16];
    int s = 0;
#pragma unroll
    for (int i = 0; i < 16; ++i) {
        int idx = base + i;
        int c = (int)((wv[i >> 2] >> ((i & 3) * 8)) & 255u);
        v[i] = (idx < NTOT4) ? c : 0;
        s += v[i];
    }
    lds[t] = s;
    __syncthreads();
    for (int off = 1; off < 256; off <<= 1) {
        int y = (t >= off) ? lds[t - off] : 0;
        __syncthreads();
        lds[t] += y;
        __syncthreads();
    }
    int run = lds[t] - s;
#pragma unroll
    for (int i = 0; i < 16; ++i) {
        int idx = base + i;
        if (idx < NTOT4) out[idx] = run;
        run += v[i];
    }
    if (t == 255) part[blockIdx.x] = lds[255];
}

__global__ void k_scan2(int* __restrict__ part, int nblk) {
    __shared__ int lds2[256];
    int t = threadIdx.x;
    int orig = (t < nblk) ? part[t] : 0;
    lds2[t] = orig;
    __syncthreads();
    for (int off = 1; off < 256; off <<= 1) {
        int y = (t >= off) ? lds2[t - off] : 0;
        __syncthreads();
        lds2[t] += y;
        __syncthreads();
    }
    if (t < nblk) part[t] = lds2[t] - orig;
}

__global__ void k_scan3(int* __restrict__ out, const int* __restrict__ part) {
    int i = blockIdx.x * blockDim.x + threadIdx.x;
    if (i >= NTOT4) return;
    out[i] += part[i / SCAN_BLK];
    if (i == 0) out[NTOT4] = N_EDGES;
}

// D5: scatter2(atomic-free, direct-to-final) | node GEMM layer-1
__global__ void __launch_bounds__(1024, 4)
k_fuse5(const int* __restrict__ src, const int* __restrict__ dst,
        const float* __restrict__ e_w, const int* __restrict__ row_off4,
        unsigned* __restrict__ csr2,
        const float* __restrict__ h, const float* __restrict__ Wself1,
        const float* __restrict__ Wfunc1, const float* __restrict__ attn1,
        __half* __restrict__ zh, float* __restrict__ hs,
        float* __restrict__ s_src, float* __restrict__ s_dst) {
    int bid = blockIdx.x;
    if (bid < NB_SCAT) { dev_scatter2(bid, src, dst, e_w, row_off4, csr2); return; }
    dev_node(bid - NB_SCAT, h, Wself1, Wfunc1, attn1, zh, hs, s_src, s_dst);
}

// standalone layer-2 node GEMM
__global__ void __launch_bounds__(1024, 4)
k_nodeL(const float* __restrict__ h, const float* __restrict__ Wself,
        const float* __restrict__ Wfunc, const float* __restrict__ attn,
        __half* __restrict__ zh, float* __restrict__ hs,
        float* __restrict__ s_src, float* __restrict__ s_dst) {
    dev_node(blockIdx.x, h, Wself, Wfunc, attn, zh, hs, s_src, s_dst);
}

// ---------------- fused edge softmax + aggregation + (optional) final projection --------
// 2 nodes per wave; eg=(lane>>3)&3, c8=lane&7; 4 edges/node/iter, half8 (16B) gathers.
// Single-pass softmax (no segment-max: |e| ~ O(0.1), exp safe; alpha identical).
__global__ void k_agg(const int* __restrict__ row_off4, const unsigned* __restrict__ csr,
                      const float* __restrict__ s_src, const float* __restrict__ s_dstA,
                      const float* __restrict__ consts, int layer,
                      const __half* __restrict__ zh, const float* __restrict__ hsb,
                      float* __restrict__ h,
                      const float* __restrict__ lin_W, const float* __restrict__ lin_b,
                      float* __restrict__ y, int final_layer) {
    int wave = threadIdx.x >> 6, lane = threadIdx.x & 63;
    int half = lane >> 5, hl = lane & 31;
    int eg = (lane >> 3) & 3, c8 = lane & 7;
    int n = blockIdx.x * 8 + wave * 2 + half;
    if (n >= N_NODES) return;
    int rs = row_off4[n * NC];
    int deg = row_off4[(n + 1) * NC] - rs;
    int degO = __shfl_xor(deg, 32);
    int degmax = deg > degO ? deg : degO;

    float c1 = consts[layer * 2 + 0];
    float c0 = consts[layer * 2 + 1];
    float sd = s_dstA[n];

    float acc[8];
#pragma unroll
    for (int k = 0; k < 8; ++k) acc[k] = 0.f;
    float ssl = 0.f;
    int lbase = lane & 32;

    for (int base = 0; base < degmax; base += 32) {
        float ex = 0.f;
        int s0 = 0;
        int idx = base + hl;
        if (idx < deg) {
            unsigned w = csr[rs + idx];
            s0 = (int)(w & 0x1FFFFu);
            float ew = (float)(w >> 17) * (1.f / 32768.f);
            float e = s_src[s0] + sd + ew * c1 + c0;
            e = (e > 0.f) ? e : NEG_SLOPE * e;
            ex = __expf(e);
        }
        ssl += ex;
        int cnt = degmax - base;
        if (cnt > 32) cnt = 32;
#pragma unroll 4
        for (int jb = 0; jb < cnt; jb += 4) {
            int srcl = lbase + jb + eg;
            int sj = __shfl(s0, srcl);
            float exj = __shfl(ex, srcl);
            half8_t zv = *(const half8_t*)(zh + ((size_t)sj << 6) + (c8 << 3));
#pragma unroll
            for (int k = 0; k < 8; ++k) acc[k] += exj * (float)zv[k];
        }
    }
#pragma unroll
    for (int k = 0; k < 8; ++k) {
        acc[k] += __shfl_xor(acc[k], 8);
        acc[k] += __shfl_xor(acc[k], 16);
    }
    ssl += __shfl_xor(ssl, 16); ssl += __shfl_xor(ssl, 8);
    ssl += __shfl_xor(ssl, 4);  ssl += __shfl_xor(ssl, 2);
    ssl += __shfl_xor(ssl, 1);

    const float4* hp = (const float4*)(h + (size_t)n * DH);
    float4 ho0 = hp[c8 * 2], ho1 = hp[c8 * 2 + 1];
    float hold[8] = {ho0.x, ho0.y, ho0.z, ho0.w, ho1.x, ho1.y, ho1.z, ho1.w};
    float hnew[8];
    if (deg == 0) {
#pragma unroll
        for (int k = 0; k < 8; ++k) hnew[k] = hold[k] + fmaxf(hold[k], 0.f);
    } else {
        float rinv = 1.f / ssl;
        const float4* sp = (const float4*)(hsb + (size_t)n * DH);
        float4 hs0 = sp[c8 * 2], hs1 = sp[c8 * 2 + 1];
        float hsv[8] = {hs0.x, hs0.y, hs0.z, hs0.w, hs1.x, hs1.y, hs1.z, hs1.w};
#pragma unroll
        for (int k = 0; k < 8; ++k)
            hnew[k] = hold[k] + fmaxf(hsv[k] + acc[k] * rinv, 0.f);
    }

    if (!final_layer) {
        if (eg == 0) {
            float4* op = (float4*)(h + (size_t)n * DH);
            op[c8 * 2]     = make_float4(hnew[0], hnew[1], hnew[2], hnew[3]);
            op[c8 * 2 + 1] = make_float4(hnew[4], hnew[5], hnew[6], hnew[7]);
        }
    } else {
#pragma unroll
        for (int t = 0; t < 3; ++t) {
            int o = eg * 3 + t;
            const float* wr = lin_W + o * DH + c8 * 8;
            float p = 0.f;
#pragma unroll
            for (int k = 0; k < 8; ++k) p += hnew[k] * wr[k];
            p += __shfl_xor(p, 1); p += __shfl_xor(p, 2); p += __shfl_xor(p, 4);
            if (c8 == 0) y[n * DOUT + o] = p + lin_b[o];
        }
    }
}

extern "C" void kernel_launch(void* const* d_in, const int* in_sizes, int n_in,
                              void* d_out, int out_size, void* d_ws, size_t ws_size,
                              hipStream_t stream) {
    const float* feats   = (const float*)d_in[0];
    const float* e_w     = (const float*)d_in[1];
    const int*   src     = (const int*)d_in[4];
    const int*   dst     = (const int*)d_in[5];
    const float* emb_h_W = (const float*)d_in[6];
    const float* emb_h_b = (const float*)d_in[7];
    const float* emb_e_W = (const float*)d_in[8];
    const float* emb_e_b = (const float*)d_in[9];
    const float* Wself[2] = {(const float*)d_in[10], (const float*)d_in[13]};
    const float* Wfunc[2] = {(const float*)d_in[11], (const float*)d_in[14]};
    const float* attn[2]  = {(const float*)d_in[12], (const float*)d_in[15]};
    const float* lin1_W  = (const float*)d_in[16];
    const float* lin1_b  = (const float*)d_in[17];
    float* y = (float*)d_out;

    char* ws = (char*)d_ws;
    size_t off = 0;
    auto alloc = [&](size_t bytes) {
        void* p = ws + off;
        off += (bytes + 255) & ~(size_t)255;
        return p;
    };
    float*         h        = (float*)alloc((size_t)N_NODES * DH * 4);
    __half*        zh       = (__half*)alloc((size_t)N_NODES * DH * 2);
    float*         hs       = (float*)alloc((size_t)N_NODES * DH * 4);
    unsigned*      csr2     = (unsigned*)alloc((size_t)N_EDGES * 4);
    float*         s_src    = (float*)alloc((size_t)N_NODES * 4);
    float*         s_dst    = (float*)alloc((size_t)N_NODES * 4);
    int*           row_off4 = (int*)alloc((size_t)(NTOT4 + 4) * 4);
    unsigned char* deg      = (unsigned char*)alloc((size_t)NTOT4 + 8192); // + scan overread pad
    int*           part     = (int*)alloc(256 * 4);
    float*         consts   = (float*)alloc(4 * 4);

    // D1: consts | hist2 (LDS, no global atomics, no memset needed) | embed
    k_fuse1<<<1 + NB_HIST2 + NB_EMBED, 1024, 0, stream>>>(feats, emb_h_W, emb_h_b, h,
                                                          dst, deg, emb_e_W, emb_e_b,
                                                          attn[0], attn[1], consts);
    // D2-D4: 400K byte-counter scan -> exact final csr positions
    k_scanB<<<NB_SCANB, 256, 0, stream>>>((const unsigned*)deg, row_off4, part);
    k_scan2<<<1, 256, 0, stream>>>(part, NB_SCANB);
    k_scan3<<<NB_SCAN3, 256, 0, stream>>>(row_off4, part);
    // D5: direct scatter (LDS cursors) | node GEMM L1
    k_fuse5<<<NB_SCAT + NB_NODE, 1024, 0, stream>>>(src, dst, e_w, row_off4, csr2,
                                                    h, Wself[0], Wfunc[0], attn[0],
                                                    zh, hs, s_src, s_dst);
    // D6: agg L1
    k_agg<<<NB_AGG, 256, 0, stream>>>(row_off4, csr2, s_src, s_dst, consts, 0,
                                      zh, hs, h, lin1_W, lin1_b, y, 0);
    // D7: node GEMM L2
    k_nodeL<<<NB_NODE, 1024, 0, stream>>>(h, Wself[1], Wfunc[1], attn[1],
                                          zh, hs, s_src, s_dst);
    // D8: agg L2 + fused final projection
    k_agg<<<NB_AGG, 256, 0, stream>>>(row_off4, csr2, s_src, s_dst, consts, 1,
                                      zh, hs, h, lin1_W, lin1_b, y, 1);
}

// Round 16
// 345.186 us; speedup vs baseline: 1.6416x; 1.6416x over previous
//
#include <hip/hip_runtime.h>
#include <hip/hip_fp16.h>

#define N_NODES 100000
#define N_EDGES 1600000
#define DIN 24
#define DH 64
#define DOUT 12
#define NEG_SLOPE 0.01f
#define NG 8                       // edge chunks (staging-CSR major axis)
#define EPG (N_EDGES / NG)         // 200000 edges per chunk
#define NS 7                       // node slices for LDS hist
#define SLICE_N 16384              // nodes per slice (16 KB byte counters)
#define NTOT (NG * N_NODES)        // 800000 c-major byte counters
#define SCAN_BLK 4096
#define LDSW 72

// role block counts
#define NB_HIST (NS * NG)                        // 56 (1024-thread blocks in D1)
#define NB_EMBED ((N_NODES * DH) / 1024)         // 6250
#define NB_SCAN1G ((NTOT + SCAN_BLK - 1) / SCAN_BLK)    // 196
#define NB_SUMDEG ((N_NODES + 255) / 256)               // 391
#define NB_SCAN1N ((N_NODES + SCAN_BLK - 1) / SCAN_BLK) // 25
#define NB_SCAN3G ((NTOT + 255) / 256)                  // 3125
#define NB_SCATTER (NG * 128)                    // 1024
#define BPE ((EPG + 127) / 128)                  // 1563 edges per scatter block
#define NB_NODE ((N_NODES + 63) / 64)            // 1563
#define NB_SCAN3N ((N_NODES + 255) / 256)        // 391
#define NB_COMPACT ((N_NODES + 31) / 32)         // 3125
#define NB_AGG ((N_NODES + 7) / 8)               // 12500

typedef _Float16 half8_t __attribute__((ext_vector_type(8)));
typedef float floatx4 __attribute__((ext_vector_type(4)));

// ---------------- role bodies ----------------
__device__ __forceinline__ void dev_consts(const float* emb_e_W, const float* emb_e_b,
                                           const float* attn1, const float* attn2,
                                           float* consts) {
    int lane = threadIdx.x;
    if (lane >= 64) return;
    float w = emb_e_W[lane], b = emb_e_b[lane];
    float a1 = attn1[2 * DH + lane], a2 = attn2[2 * DH + lane];
    float c11 = w * a1, c01 = b * a1, c12 = w * a2, c02 = b * a2;
    for (int off = 32; off; off >>= 1) {
        c11 += __shfl_down(c11, off);
        c01 += __shfl_down(c01, off);
        c12 += __shfl_down(c12, off);
        c02 += __shfl_down(c02, off);
    }
    if (lane == 0) {
        consts[0] = c11; consts[1] = c01; consts[2] = c12; consts[3] = c02;
    }
}

// slice-LDS histogram + rank capture, ZERO global atomics.
// Round-14 lesson: 1.6M global atomics = ~100us floor (32B write-through/op).
// Round-15 lesson: slice-filtering must amplify only the CHEAP pass — here the
// hist re-reads dst NS=7x (45 MB, L2/L3-fed), while scatter stays 1-pass.
// Block (s,c): LDS byte counters for its 16384-node slice; the returned old
// byte IS the edge's rank within its (chunk,node) sub-list.
__device__ __forceinline__ void dev_hist(int bid, const int* dst,
                                         unsigned char* deg, unsigned char* rank) {
    __shared__ unsigned cnt[SLICE_N / 4];   // 16 KB byte-packed
    int s = bid % NS, c = bid / NS;
    for (int i = threadIdx.x; i < SLICE_N / 4; i += 1024) cnt[i] = 0;
    __syncthreads();
    int nbase = s * SLICE_N;
    int start = c * EPG, end = start + EPG;
    for (int i = start + threadIdx.x; i < end; i += 1024) {
        int local = dst[i] - nbase;
        if ((unsigned)local < SLICE_N) {
            unsigned sh = (unsigned)(local & 3) * 8u;
            unsigned old = atomicAdd(&cnt[local >> 2], 1u << sh);  // LDS atomic
            rank[i] = (unsigned char)((old >> sh) & 255u);
        }
    }
    __syncthreads();
    const unsigned char* cb = (const unsigned char*)cnt;
    for (int l = threadIdx.x; l < SLICE_N; l += 1024) {
        int n = nbase + l;
        if (n < N_NODES) deg[c * N_NODES + n] = cb[l];   // exclusive coalesced flush
    }
}

__device__ __forceinline__ void dev_embed(int bid, const float* feats, const float* W,
                                          const float* b, float* h) {
    int idx = bid * 1024 + threadIdx.x;
    if (idx >= N_NODES * DH) return;
    int n = idx >> 6, o = idx & 63;
    const float* f = feats + n * DIN;
    const float* w = W + o * DIN;
    float acc = b[o];
#pragma unroll
    for (int k = 0; k < DIN; ++k) acc += f[k] * w[k];
    h[idx] = acc;
}

// exclusive scan over BYTE counters (16 bytes = 4 words per thread)
__device__ __forceinline__ void dev_scan1B(int bid, const unsigned* inW, int* out,
                                           int* part, int n) {
    __shared__ int lds[256];
    int t = threadIdx.x;
    int base = bid * SCAN_BLK + t * 16;
    unsigned wv[4];
#pragma unroll
    for (int i = 0; i < 4; ++i) wv[i] = inW[(base >> 2) + i];  // padded alloc
    int v[16];
    int s = 0;
#pragma unroll
    for (int i = 0; i < 16; ++i) {
        int idx = base + i;
        int c = (int)((wv[i >> 2] >> ((i & 3) * 8)) & 255u);
        v[i] = (idx < n) ? c : 0;
        s += v[i];
    }
    lds[t] = s;
    __syncthreads();
    for (int off = 1; off < 256; off <<= 1) {
        int y = (t >= off) ? lds[t - off] : 0;
        __syncthreads();
        lds[t] += y;
        __syncthreads();
    }
    int run = lds[t] - s;
#pragma unroll
    for (int i = 0; i < 16; ++i) {
        int idx = base + i;
        if (idx < n) out[idx] = run;
        run += v[i];
    }
    if (t == 255) part[bid] = lds[255];
}

__device__ __forceinline__ void dev_scan1(int bid, const int* in, int* out,
                                          int* part, int n) {
    __shared__ int lds[256];
    int t = threadIdx.x;
    int base = bid * SCAN_BLK + t * 16;
    int v[16];
    int s = 0;
#pragma unroll
    for (int i = 0; i < 16; ++i) {
        int idx = base + i;
        v[i] = (idx < n) ? in[idx] : 0;
        s += v[i];
    }
    lds[t] = s;
    __syncthreads();
    for (int off = 1; off < 256; off <<= 1) {
        int y = (t >= off) ? lds[t - off] : 0;
        __syncthreads();
        lds[t] += y;
        __syncthreads();
    }
    int run = lds[t] - s;
#pragma unroll
    for (int i = 0; i < 16; ++i) {
        int idx = base + i;
        if (idx < n) out[idx] = run;
        run += v[i];
    }
    if (t == 255) part[bid] = lds[255];
}

__device__ __forceinline__ void dev_scan2(int* part, int nblk) {
    __shared__ int lds2[256];
    int t = threadIdx.x;
    int orig = (t < nblk) ? part[t] : 0;
    lds2[t] = orig;
    __syncthreads();
    for (int off = 1; off < 256; off <<= 1) {
        int y = (t >= off) ? lds2[t - off] : 0;
        __syncthreads();
        lds2[t] += y;
        __syncthreads();
    }
    if (t < nblk) part[t] = lds2[t] - orig;
}

__device__ __forceinline__ void dev_sumdeg(int bid, const unsigned char* degB, int* degN) {
    int n = bid * 256 + threadIdx.x;
    if (n >= N_NODES) return;
    int s = 0;
#pragma unroll
    for (int g = 0; g < NG; ++g) s += (int)degB[g * N_NODES + n];
    degN[n] = s;
}

// atomic-free staged scatter: pos = row_offG[c*N+d] + rank[i]
__device__ __forceinline__ void dev_scatter(int bid, const int* src, const int* dst,
                                            const float* e_w, const unsigned char* rank,
                                            const int* row_offG, unsigned* csr) {
    int g = bid & 7, q = bid >> 3;
    int start = g * EPG + q * BPE;
    int end = start + BPE;
    int gend = (g + 1) * EPG;
    if (end > gend) end = gend;
    const int* ro = row_offG + g * N_NODES;
    for (int i = start + threadIdx.x; i < end; i += 256) {
        int d = dst[i];
        unsigned qv = (unsigned)(e_w[i] * 32768.f);
        if (qv > 32767u) qv = 32767u;
        unsigned w = (unsigned)src[i] | (qv << 17);
        int pos = ro[d] + (int)rank[i];
        csr[pos] = w;
    }
}

// MFMA node GEMM: 16 nodes/wave, weights fp16 in LDS
__device__ __forceinline__ void dev_node(int bid, const float* h,
                                         const float* Wself, const float* Wfunc,
                                         const float* attn,
                                         __half* zh, float* hs,
                                         float* s_src, float* s_dst) {
    __shared__ _Float16 lds[2 * 64 * LDSW];
    int tid = threadIdx.x;
    for (int idx = tid; idx < 2 * 64 * 64; idx += 256) {
        int mat = idx >> 12, rem = idx & 4095;
        int o = rem >> 6, k = rem & 63;
        float v = mat ? Wfunc[rem] : Wself[rem];
        lds[(mat * 64 + o) * LDSW + k] = (_Float16)v;
    }
    __syncthreads();

    int wave = tid >> 6, lane = tid & 63;
    int n0 = (bid * 4 + wave) * 16;
    if (n0 >= N_NODES) return;
    int quad = lane >> 4, lm = lane & 15;

    half8_t afrag[2];
    {
        const float4* hrow = (const float4*)(h + (size_t)(n0 + lm) * DH);
#pragma unroll
        for (int ks = 0; ks < 2; ++ks) {
            float4 p0 = hrow[ks * 8 + quad * 2];
            float4 p1 = hrow[ks * 8 + quad * 2 + 1];
            half8_t a;
            a[0] = (_Float16)p0.x; a[1] = (_Float16)p0.y;
            a[2] = (_Float16)p0.z; a[3] = (_Float16)p0.w;
            a[4] = (_Float16)p1.x; a[5] = (_Float16)p1.y;
            a[6] = (_Float16)p1.z; a[7] = (_Float16)p1.w;
            afrag[ks] = a;
        }
    }

    floatx4 accS[4], accF[4];
#pragma unroll
    for (int t = 0; t < 4; ++t) { accS[t] = (floatx4)0.f; accF[t] = (floatx4)0.f; }

    const _Float16* bS = lds;
    const _Float16* bF = lds + 64 * LDSW;
#pragma unroll
    for (int t = 0; t < 4; ++t) {
        int o = t * 16 + lm;
#pragma unroll
        for (int ks = 0; ks < 2; ++ks) {
            int hoff = o * LDSW + ks * 32 + quad * 8;
            half8_t b1 = *(const half8_t*)(bS + hoff);
            half8_t b2 = *(const half8_t*)(bF + hoff);
            accS[t] = __builtin_amdgcn_mfma_f32_16x16x32_f16(afrag[ks], b1, accS[t], 0, 0, 0);
            accF[t] = __builtin_amdgcn_mfma_f32_16x16x32_f16(afrag[ks], b2, accF[t], 0, 0, 0);
        }
    }

    float asv[4], adv[4];
#pragma unroll
    for (int t = 0; t < 4; ++t) {
        asv[t] = attn[t * 16 + lm];
        adv[t] = attn[DH + t * 16 + lm];
    }
    float ps[4] = {0.f, 0.f, 0.f, 0.f}, pd[4] = {0.f, 0.f, 0.f, 0.f};
#pragma unroll
    for (int t = 0; t < 4; ++t) {
#pragma unroll
        for (int r = 0; r < 4; ++r) {
            int node = n0 + quad * 4 + r;
            float zv = accF[t][r];
            zh[(size_t)node * DH + t * 16 + lm] = __float2half(zv);
            hs[(size_t)node * DH + t * 16 + lm] = accS[t][r];
            ps[r] += zv * asv[t];
            pd[r] += zv * adv[t];
        }
    }
#pragma unroll
    for (int r = 0; r < 4; ++r) {
        float p1 = ps[r], p2 = pd[r];
        for (int off = 8; off; off >>= 1) {
            p1 += __shfl_xor(p1, off);
            p2 += __shfl_xor(p2, off);
        }
        if (lm == 0) {
            s_src[n0 + quad * 4 + r] = p1;
            s_dst[n0 + quad * 4 + r] = p2;
        }
    }
}

// ---------------- fused dispatches ----------------
// D1 (1024 thr): consts | hist(slice-LDS, +rank) | embed
__global__ void __launch_bounds__(1024, 2)
k_fuse1(const float* __restrict__ feats, const float* __restrict__ emb_h_W,
        const float* __restrict__ emb_h_b, float* __restrict__ h,
        const int* __restrict__ dst, unsigned char* __restrict__ deg,
        unsigned char* __restrict__ rank,
        const float* __restrict__ emb_e_W, const float* __restrict__ emb_e_b,
        const float* __restrict__ attn1, const float* __restrict__ attn2,
        float* __restrict__ consts) {
    int bid = blockIdx.x;
    if (bid == 0) { dev_consts(emb_e_W, emb_e_b, attn1, attn2, consts); return; }
    bid -= 1;
    if (bid < NB_HIST) { dev_hist(bid, dst, deg, rank); return; }
    dev_embed(bid - NB_HIST, feats, emb_h_W, emb_h_b, h);
}

// D2: scan1G(bytes) | sumdeg(bytes)
__global__ void k_fuse2(const unsigned* __restrict__ degW, int* __restrict__ row_offG,
                        int* __restrict__ partG, int* __restrict__ degN) {
    int bid = blockIdx.x;
    if (bid < NB_SCAN1G) { dev_scan1B(bid, degW, row_offG, partG, NTOT); return; }
    dev_sumdeg(bid - NB_SCAN1G, (const unsigned char*)degW, degN);
}

// D3: scan2G | scan1N
__global__ void k_fuse3(int* __restrict__ partG, const int* __restrict__ degN,
                        int* __restrict__ row_offN, int* __restrict__ partN) {
    int bid = blockIdx.x;
    if (bid == 0) { dev_scan2(partG, NB_SCAN1G); return; }
    dev_scan1(bid - 1, degN, row_offN, partN, N_NODES);
}

// D4: scan2N | scan3G (finalize row_offG)
__global__ void k_fuse4(int* __restrict__ row_offG, const int* __restrict__ partG,
                        int* __restrict__ partN) {
    int bid = blockIdx.x;
    if (bid == 0) { dev_scan2(partN, NB_SCAN1N); return; }
    int i = (bid - 1) * 256 + threadIdx.x;
    if (i >= NTOT) return;
    row_offG[i] += partG[i / SCAN_BLK];
    if (i == 0) row_offG[NTOT] = N_EDGES;
}

// D5: scatter(atomic-free) | node GEMM layer-1 | scan3N
__global__ void __launch_bounds__(256, 4)
k_fuse5(const int* __restrict__ src, const int* __restrict__ dst,
        const float* __restrict__ e_w, const unsigned char* __restrict__ rank,
        const int* __restrict__ row_offG, unsigned* __restrict__ csr,
        int* __restrict__ row_offN, const int* __restrict__ partN,
        const float* __restrict__ h, const float* __restrict__ Wself1,
        const float* __restrict__ Wfunc1, const float* __restrict__ attn1,
        __half* __restrict__ zh, float* __restrict__ hs,
        float* __restrict__ s_src, float* __restrict__ s_dst) {
    int bid = blockIdx.x;
    if (bid < NB_SCATTER) { dev_scatter(bid, src, dst, e_w, rank, row_offG, csr); return; }
    bid -= NB_SCATTER;
    if (bid < NB_NODE) { dev_node(bid, h, Wself1, Wfunc1, attn1, zh, hs, s_src, s_dst); return; }
    int i = (bid - NB_NODE) * 256 + threadIdx.x;
    if (i >= N_NODES) return;
    row_offN[i] += partN[i / SCAN_BLK];
    if (i == 0) row_offN[N_NODES] = N_EDGES;
}

// c-major csr -> node-contiguous csr2 (staged+compact is the measured optimum)
__global__ void k_compact(const int* __restrict__ row_offG, const int* __restrict__ row_offN,
                          const unsigned* __restrict__ csr, unsigned* __restrict__ csr2) {
    int wave = threadIdx.x >> 6, lane = threadIdx.x & 63;
    int n0 = (blockIdx.x * 4 + wave) * 8;
    if (n0 >= N_NODES) return;
    int g = lane & 7, nl = lane >> 3;
    int n = n0 + nl;
    int offG = 0, dg = 0;
    if (n < N_NODES) {
        int idx = g * N_NODES + n;
        offG = row_offG[idx];
        dg = row_offG[idx + 1] - offG;
    }
    int x = dg;
#pragma unroll
    for (int s = 1; s < 8; s <<= 1) {
        int y = __shfl_up(x, s);
        if ((lane & 7) >= s) x += y;
    }
    if (n < N_NODES) {
        int base = row_offN[n] + (x - dg);
        for (int j = 0; j < dg; ++j) csr2[base + j] = csr[offG + j];
    }
}

// standalone layer-2 node GEMM
__global__ void __launch_bounds__(256, 4)
k_nodeL(const float* __restrict__ h, const float* __restrict__ Wself,
        const float* __restrict__ Wfunc, const float* __restrict__ attn,
        __half* __restrict__ zh, float* __restrict__ hs,
        float* __restrict__ s_src, float* __restrict__ s_dst) {
    dev_node(blockIdx.x, h, Wself, Wfunc, attn, zh, hs, s_src, s_dst);
}

// ---------------- fused edge softmax + aggregation + (optional) final projection --------
__global__ void k_agg(const int* __restrict__ row_off, const unsigned* __restrict__ csr,
                      const float* __restrict__ s_src, const float* __restrict__ s_dstA,
                      const float* __restrict__ consts, int layer,
                      const __half* __restrict__ zh, const float* __restrict__ hsb,
                      float* __restrict__ h,
                      const float* __restrict__ lin_W, const float* __restrict__ lin_b,
                      float* __restrict__ y, int final_layer) {
    int wave = threadIdx.x >> 6, lane = threadIdx.x & 63;
    int half = lane >> 5, hl = lane & 31;
    int eg = (lane >> 3) & 3, c8 = lane & 7;
    int n = blockIdx.x * 8 + wave * 2 + half;
    if (n >= N_NODES) return;
    int rs = row_off[n], deg = row_off[n + 1] - rs;
    int degO = __shfl_xor(deg, 32);
    int degmax = deg > degO ? deg : degO;

    float c1 = consts[layer * 2 + 0];
    float c0 = consts[layer * 2 + 1];
    float sd = s_dstA[n];

    float acc[8];
#pragma unroll
    for (int k = 0; k < 8; ++k) acc[k] = 0.f;
    float ssl = 0.f;
    int lbase = lane & 32;

    for (int base = 0; base < degmax; base += 32) {
        float ex = 0.f;
        int s0 = 0;
        int idx = base + hl;
        if (idx < deg) {
            unsigned w = csr[rs + idx];
            s0 = (int)(w & 0x1FFFFu);
            float ew = (float)(w >> 17) * (1.f / 32768.f);
            float e = s_src[s0] + sd + ew * c1 + c0;
            e = (e > 0.f) ? e : NEG_SLOPE * e;
            ex = __expf(e);
        }
        ssl += ex;
        int cnt = degmax - base;
        if (cnt > 32) cnt = 32;
#pragma unroll 4
        for (int jb = 0; jb < cnt; jb += 4) {
            int srcl = lbase + jb + eg;
            int sj = __shfl(s0, srcl);
            float exj = __shfl(ex, srcl);
            half8_t zv = *(const half8_t*)(zh + ((size_t)sj << 6) + (c8 << 3));
#pragma unroll
            for (int k = 0; k < 8; ++k) acc[k] += exj * (float)zv[k];
        }
    }
#pragma unroll
    for (int k = 0; k < 8; ++k) {
        acc[k] += __shfl_xor(acc[k], 8);
        acc[k] += __shfl_xor(acc[k], 16);
    }
    ssl += __shfl_xor(ssl, 16); ssl += __shfl_xor(ssl, 8);
    ssl += __shfl_xor(ssl, 4);  ssl += __shfl_xor(ssl, 2);
    ssl += __shfl_xor(ssl, 1);

    const float4* hp = (const float4*)(h + (size_t)n * DH);
    float4 ho0 = hp[c8 * 2], ho1 = hp[c8 * 2 + 1];
    float hold[8] = {ho0.x, ho0.y, ho0.z, ho0.w, ho1.x, ho1.y, ho1.z, ho1.w};
    float hnew[8];
    if (deg == 0) {
#pragma unroll
        for (int k = 0; k < 8; ++k) hnew[k] = hold[k] + fmaxf(hold[k], 0.f);
    } else {
        float rinv = 1.f / ssl;
        const float4* sp = (const float4*)(hsb + (size_t)n * DH);
        float4 hs0 = sp[c8 * 2], hs1 = sp[c8 * 2 + 1];
        float hsv[8] = {hs0.x, hs0.y, hs0.z, hs0.w, hs1.x, hs1.y, hs1.z, hs1.w};
#pragma unroll
        for (int k = 0; k < 8; ++k)
            hnew[k] = hold[k] + fmaxf(hsv[k] + acc[k] * rinv, 0.f);
    }

    if (!final_layer) {
        if (eg == 0) {
            float4* op = (float4*)(h + (size_t)n * DH);
            op[c8 * 2]     = make_float4(hnew[0], hnew[1], hnew[2], hnew[3]);
            op[c8 * 2 + 1] = make_float4(hnew[4], hnew[5], hnew[6], hnew[7]);
        }
    } else {
#pragma unroll
        for (int t = 0; t < 3; ++t) {
            int o = eg * 3 + t;
            const float* wr = lin_W + o * DH + c8 * 8;
            float p = 0.f;
#pragma unroll
            for (int k = 0; k < 8; ++k) p += hnew[k] * wr[k];
            p += __shfl_xor(p, 1); p += __shfl_xor(p, 2); p += __shfl_xor(p, 4);
            if (c8 == 0) y[n * DOUT + o] = p + lin_b[o];
        }
    }
}

extern "C" void kernel_launch(void* const* d_in, const int* in_sizes, int n_in,
                              void* d_out, int out_size, void* d_ws, size_t ws_size,
                              hipStream_t stream) {
    const float* feats   = (const float*)d_in[0];
    const float* e_w     = (const float*)d_in[1];
    const int*   src     = (const int*)d_in[4];
    const int*   dst     = (const int*)d_in[5];
    const float* emb_h_W = (const float*)d_in[6];
    const float* emb_h_b = (const float*)d_in[7];
    const float* emb_e_W = (const float*)d_in[8];
    const float* emb_e_b = (const float*)d_in[9];
    const float* Wself[2] = {(const float*)d_in[10], (const float*)d_in[13]};
    const float* Wfunc[2] = {(const float*)d_in[11], (const float*)d_in[14]};
    const float* attn[2]  = {(const float*)d_in[12], (const float*)d_in[15]};
    const float* lin1_W  = (const float*)d_in[16];
    const float* lin1_b  = (const float*)d_in[17];
    float* y = (float*)d_out;

    char* ws = (char*)d_ws;
    size_t off = 0;
    auto alloc = [&](size_t bytes) {
        void* p = ws + off;
        off += (bytes + 255) & ~(size_t)255;
        return p;
    };
    float*         h        = (float*)alloc((size_t)N_NODES * DH * 4);
    __half*        zh       = (__half*)alloc((size_t)N_NODES * DH * 2);
    float*         hs       = (float*)alloc((size_t)N_NODES * DH * 4);
    unsigned*      csr      = (unsigned*)alloc((size_t)N_EDGES * 4);
    unsigned*      csr2     = (unsigned*)alloc((size_t)N_EDGES * 4);
    float*         s_src    = (float*)alloc((size_t)N_NODES * 4);
    float*         s_dst    = (float*)alloc((size_t)N_NODES * 4);
    int*           row_offG = (int*)alloc((size_t)(NTOT + 1) * 4);
    int*           row_offN = (int*)alloc((size_t)(N_NODES + 1) * 4);
    unsigned char* deg      = (unsigned char*)alloc((size_t)NTOT + 8192); // + scan overread pad
    unsigned char* rank     = (unsigned char*)alloc((size_t)N_EDGES);
    int*           degN     = (int*)alloc((size_t)N_NODES * 4);
    int*           partG    = (int*)alloc(256 * 4);
    int*           partN    = (int*)alloc(256 * 4);
    float*         consts   = (float*)alloc(4 * 4);

    // D1: consts | slice-LDS hist(+rank, no global atomics, no memset) | embed
    k_fuse1<<<1 + NB_HIST + NB_EMBED, 1024, 0, stream>>>(feats, emb_h_W, emb_h_b, h,
                                                         dst, deg, rank, emb_e_W, emb_e_b,
                                                         attn[0], attn[1], consts);
    // D2: scan1G(bytes) | sumdeg
    k_fuse2<<<NB_SCAN1G + NB_SUMDEG, 256, 0, stream>>>((const unsigned*)deg, row_offG,
                                                       partG, degN);
    // D3: scan2G | scan1N
    k_fuse3<<<1 + NB_SCAN1N, 256, 0, stream>>>(partG, degN, row_offN, partN);
    // D4: scan2N | scan3G
    k_fuse4<<<1 + NB_SCAN3G, 256, 0, stream>>>(row_offG, partG, partN);
    // D5: scatter(atomic-free) | node GEMM L1 | scan3N
    k_fuse5<<<NB_SCATTER + NB_NODE + NB_SCAN3N, 256, 0, stream>>>(
        src, dst, e_w, rank, row_offG, csr, row_offN, partN,
        h, Wself[0], Wfunc[0], attn[0], zh, hs, s_src, s_dst);
    // D6: compact
    k_compact<<<NB_COMPACT, 256, 0, stream>>>(row_offG, row_offN, csr, csr2);
    // D7: agg L1
    k_agg<<<NB_AGG, 256, 0, stream>>>(row_offN, csr2, s_src, s_dst, consts, 0,
                                      zh, hs, h, lin1_W, lin1_b, y, 0);
    // D8: node GEMM L2
    k_nodeL<<<NB_NODE, 256, 0, stream>>>(h, Wself[1], Wfunc[1], attn[1],
                                         zh, hs, s_src, s_dst);
    // D9: agg L2 + fused final projection
    k_agg<<<NB_AGG, 256, 0, stream>>>(row_offN, csr2, s_src, s_dst, consts, 1,
                                      zh, hs, h, lin1_W, lin1_b, y, 1);
}